// Round 1
// baseline (11770.503 us; speedup 1.0000x reference)
//
#include <hip/hip_runtime.h>
#include <cstdint>

#define NFEAT 512
#define NHID 256
#define NCLASS 64

// ---------------- tiled fp32 GEMM: C[M,N] = A[M,K] @ B[K,N] (+optional relu on A load)
#define BM 64
#define BN 64
#define BK 16

template<bool RELU_A>
__global__ __launch_bounds__(256)
void gemm_tiled(const float* __restrict__ A, const float* __restrict__ B,
                float* __restrict__ C, int M, int N, int K) {
  __shared__ float As[BK][BM + 4];   // stride 68 floats = 272B (16B-multiple -> aligned float4)
  __shared__ float Bs[BK][BN + 4];
  const int bm = blockIdx.x * BM;
  const int bn = blockIdx.y * BN;
  const int t  = threadIdx.x;
  const int tx = t & 15;             // 0..15  (N direction, 4 cols each)
  const int ty = t >> 4;             // 0..15  (M direction, 4 rows each)

  const int ar = t >> 2;             // 0..63 : A tile row
  const int ac = (t & 3) << 2;       // 0,4,8,12 : A tile col (float4)
  const int br = t >> 4;             // 0..15 : B tile row
  const int bc = (t & 15) << 2;      // 0..60 : B tile col (float4)

  float acc[4][4] = {};

  for (int k0 = 0; k0 < K; k0 += BK) {
    float4 av = make_float4(0.f, 0.f, 0.f, 0.f);
    const int arow = bm + ar;
    if (arow < M) av = *(const float4*)(A + (size_t)arow * K + (k0 + ac));
    if (RELU_A) {
      av.x = fmaxf(av.x, 0.f); av.y = fmaxf(av.y, 0.f);
      av.z = fmaxf(av.z, 0.f); av.w = fmaxf(av.w, 0.f);
    }
    As[ac + 0][ar] = av.x;
    As[ac + 1][ar] = av.y;
    As[ac + 2][ar] = av.z;
    As[ac + 3][ar] = av.w;

    const float4 bv = *(const float4*)(B + (size_t)(k0 + br) * N + (bn + bc));
    *(float4*)(&Bs[br][bc]) = bv;

    __syncthreads();
#pragma unroll
    for (int kk = 0; kk < BK; ++kk) {
      const float4 a = *(const float4*)(&As[kk][ty << 2]);
      const float4 b = *(const float4*)(&Bs[kk][tx << 2]);
      acc[0][0] += a.x * b.x; acc[0][1] += a.x * b.y; acc[0][2] += a.x * b.z; acc[0][3] += a.x * b.w;
      acc[1][0] += a.y * b.x; acc[1][1] += a.y * b.y; acc[1][2] += a.y * b.z; acc[1][3] += a.y * b.w;
      acc[2][0] += a.z * b.x; acc[2][1] += a.z * b.y; acc[2][2] += a.z * b.z; acc[2][3] += a.z * b.w;
      acc[3][0] += a.w * b.x; acc[3][1] += a.w * b.y; acc[3][2] += a.w * b.z; acc[3][3] += a.w * b.w;
    }
    __syncthreads();
  }

#pragma unroll
  for (int i = 0; i < 4; ++i) {
    const int crow = bm + (ty << 2) + i;
    if (crow < M) {
      float4 o = make_float4(acc[i][0], acc[i][1], acc[i][2], acc[i][3]);
      *(float4*)(C + (size_t)crow * N + bn + (tx << 2)) = o;
    }
  }
}

// ---------------- init out buffer with broadcast bias
__global__ __launch_bounds__(256)
void init_bias(float* __restrict__ out, const float* __restrict__ bias,
               int total4, int dmask) {
  const int i = blockIdx.x * 256 + threadIdx.x;
  if (i >= total4) return;
  const int base = i << 2;
  const float4 b = *(const float4*)(bias + (base & dmask));
  *(float4*)(out + (size_t)base) = b;
}

// ---------------- SpMM via per-edge atomics, D=256 (one wave per edge, float4/lane)
__global__ __launch_bounds__(256)
void spmm_atomic_d256(const int* __restrict__ rows, const int* __restrict__ cols,
                      const float* __restrict__ vals, const float* __restrict__ dense,
                      float* __restrict__ out, int E) {
  const int gid  = blockIdx.x * 256 + threadIdx.x;
  const int e    = gid >> 6;
  if (e >= E) return;
  const int lane = gid & 63;
  const int c = cols[e];
  const int r = rows[e];
  const float v = vals[e];
  const float4 g = *(const float4*)(dense + (size_t)c * 256 + (lane << 2));
  float* o = out + (size_t)r * 256 + (lane << 2);
  atomicAdd(o + 0, v * g.x);
  atomicAdd(o + 1, v * g.y);
  atomicAdd(o + 2, v * g.z);
  atomicAdd(o + 3, v * g.w);
}

// ---------------- SpMM via per-edge atomics, D=64 (one wave per edge, 1 float/lane)
__global__ __launch_bounds__(256)
void spmm_atomic_d64(const int* __restrict__ rows, const int* __restrict__ cols,
                     const float* __restrict__ vals, const float* __restrict__ dense,
                     float* __restrict__ out, int E) {
  const int gid  = blockIdx.x * 256 + threadIdx.x;
  const int e    = gid >> 6;
  if (e >= E) return;
  const int lane = gid & 63;
  const int c = cols[e];
  const int r = rows[e];
  const float v = vals[e];
  const float g = dense[(size_t)c * 64 + lane];
  atomicAdd(out + (size_t)r * 64 + lane, v * g);
}

// ---------------- row log-softmax over 64 classes (one wave per row)
__global__ __launch_bounds__(256)
void logsoftmax_k(float* __restrict__ out, int Nrows) {
  const int gid  = blockIdx.x * 256 + threadIdx.x;
  const int row  = gid >> 6;
  if (row >= Nrows) return;
  const int lane = gid & 63;
  const float v = out[(size_t)row * 64 + lane];
  float m = v;
#pragma unroll
  for (int off = 32; off; off >>= 1) m = fmaxf(m, __shfl_xor(m, off));
  const float e = __expf(v - m);
  float s = e;
#pragma unroll
  for (int off = 32; off; off >>= 1) s += __shfl_xor(s, off);
  out[(size_t)row * 64 + lane] = v - m - __logf(s);
}

extern "C" void kernel_launch(void* const* d_in, const int* in_sizes, int n_in,
                              void* d_out, int out_size, void* d_ws, size_t ws_size,
                              hipStream_t stream) {
  const float* x   = (const float*)d_in[0];
  const int*   a1r = (const int*)d_in[1];
  const int*   a1c = (const int*)d_in[2];
  const float* a1v = (const float*)d_in[3];
  const int*   a2r = (const int*)d_in[4];
  const int*   a2c = (const int*)d_in[5];
  const float* a2v = (const float*)d_in[6];
  const float* W1  = (const float*)d_in[7];
  const float* b1  = (const float*)d_in[8];
  const float* W2  = (const float*)d_in[9];
  const float* b2  = (const float*)d_in[10];
  float* out = (float*)d_out;

  const int M  = in_sizes[0] / NFEAT;   // 100000
  const int E1 = in_sizes[1];           // 3200000
  const int E2 = in_sizes[4];

  float* support = (float*)d_ws;  // [M,NHID] for layer1, reused as [M,NCLASS] for layer2
  float* h = (float*)((char*)d_ws + (size_t)M * NHID * sizeof(float));  // [M,NHID]

  // 1) support1 = x @ W1
  {
    dim3 grid((M + BM - 1) / BM, NHID / BN);
    gemm_tiled<false><<<grid, 256, 0, stream>>>(x, W1, support, M, NHID, NFEAT);
  }
  // 2) h = b1 (broadcast)
  {
    const int total4 = M * NHID / 4;
    init_bias<<<(total4 + 255) / 256, 256, 0, stream>>>(h, b1, total4, NHID - 1);
  }
  // 3) h += adj1 @ support1
  {
    const int nthreads = E1 * 64;
    spmm_atomic_d256<<<(nthreads + 255) / 256, 256, 0, stream>>>(a1r, a1c, a1v, support, h, E1);
  }
  // 4) support2 = relu(h) @ W2
  {
    dim3 grid((M + BM - 1) / BM, NCLASS / BN);
    gemm_tiled<true><<<grid, 256, 0, stream>>>(h, W2, support, M, NCLASS, NHID);
  }
  // 5) out = b2 (broadcast)
  {
    const int total4 = M * NCLASS / 4;
    init_bias<<<(total4 + 255) / 256, 256, 0, stream>>>(out, b2, total4, NCLASS - 1);
  }
  // 6) out += adj2 @ support2
  {
    const int nthreads = E2 * 64;
    spmm_atomic_d64<<<(nthreads + 255) / 256, 256, 0, stream>>>(a2r, a2c, a2v, support, out, E2);
  }
  // 7) log_softmax rows
  {
    const int nthreads = M * 64;
    logsoftmax_k<<<(nthreads + 255) / 256, 256, 0, stream>>>(out, M);
  }
}

// Round 2
// 1798.107 us; speedup vs baseline: 6.5461x; 6.5461x over previous
//
#include <hip/hip_runtime.h>
#include <cstdint>

#define NFEAT 512
#define NHID 256
#define NCLASS 64

// ---------------- tiled fp32 GEMM: C[M,N] = A[M,K] @ B[K,N]
#define BM 64
#define BN 64
#define BK 16

template<bool RELU_A>
__global__ __launch_bounds__(256)
void gemm_tiled(const float* __restrict__ A, const float* __restrict__ B,
                float* __restrict__ C, int M, int N, int K) {
  __shared__ float As[BK][BM + 4];
  __shared__ float Bs[BK][BN + 4];
  const int bm = blockIdx.x * BM;
  const int bn = blockIdx.y * BN;
  const int t  = threadIdx.x;
  const int tx = t & 15;
  const int ty = t >> 4;

  const int ar = t >> 2;
  const int ac = (t & 3) << 2;
  const int br = t >> 4;
  const int bc = (t & 15) << 2;

  float acc[4][4] = {};

  for (int k0 = 0; k0 < K; k0 += BK) {
    float4 av = make_float4(0.f, 0.f, 0.f, 0.f);
    const int arow = bm + ar;
    if (arow < M) av = *(const float4*)(A + (size_t)arow * K + (k0 + ac));
    if (RELU_A) {
      av.x = fmaxf(av.x, 0.f); av.y = fmaxf(av.y, 0.f);
      av.z = fmaxf(av.z, 0.f); av.w = fmaxf(av.w, 0.f);
    }
    As[ac + 0][ar] = av.x;
    As[ac + 1][ar] = av.y;
    As[ac + 2][ar] = av.z;
    As[ac + 3][ar] = av.w;

    const float4 bv = *(const float4*)(B + (size_t)(k0 + br) * N + (bn + bc));
    *(float4*)(&Bs[br][bc]) = bv;

    __syncthreads();
#pragma unroll
    for (int kk = 0; kk < BK; ++kk) {
      const float4 a = *(const float4*)(&As[kk][ty << 2]);
      const float4 b = *(const float4*)(&Bs[kk][tx << 2]);
      acc[0][0] += a.x * b.x; acc[0][1] += a.x * b.y; acc[0][2] += a.x * b.z; acc[0][3] += a.x * b.w;
      acc[1][0] += a.y * b.x; acc[1][1] += a.y * b.y; acc[1][2] += a.y * b.z; acc[1][3] += a.y * b.w;
      acc[2][0] += a.z * b.x; acc[2][1] += a.z * b.y; acc[2][2] += a.z * b.z; acc[2][3] += a.z * b.w;
      acc[3][0] += a.w * b.x; acc[3][1] += a.w * b.y; acc[3][2] += a.w * b.z; acc[3][3] += a.w * b.w;
    }
    __syncthreads();
  }

#pragma unroll
  for (int i = 0; i < 4; ++i) {
    const int crow = bm + (ty << 2) + i;
    if (crow < M) {
      float4 o = make_float4(acc[i][0], acc[i][1], acc[i][2], acc[i][3]);
      *(float4*)(C + (size_t)crow * N + bn + (tx << 2)) = o;
    }
  }
}

// ---------------- CSR build: zero, histogram, 3-phase scan, scatter
__global__ __launch_bounds__(256)
void zero_ints(int* __restrict__ p, int n) {
  const int i = blockIdx.x * 256 + threadIdx.x;
  if (i < n) p[i] = 0;
}

__global__ __launch_bounds__(256)
void hist_k(const int* __restrict__ rows, int* __restrict__ cnt, int E) {
  const int i = blockIdx.x * 256 + threadIdx.x;
  if (i < E) atomicAdd(&cnt[rows[i]], 1);
}

// block b sums cnt[b*1024 .. b*1024+1023]
__global__ __launch_bounds__(256)
void scan_partial_k(const int* __restrict__ cnt, int* __restrict__ partial, int M) {
  __shared__ int red[256];
  const int b = blockIdx.x, t = threadIdx.x;
  const int base = b * 1024 + t * 4;
  int s = 0;
#pragma unroll
  for (int i = 0; i < 4; ++i) { const int idx = base + i; if (idx < M) s += cnt[idx]; }
  red[t] = s; __syncthreads();
  for (int off = 128; off; off >>= 1) { if (t < off) red[t] += red[t + off]; __syncthreads(); }
  if (t == 0) partial[b] = red[0];
}

// single block: in-place exclusive scan of partial[0..G), G <= 256
__global__ __launch_bounds__(256)
void scan_offsets_k(int* __restrict__ partial, int G) {
  __shared__ int buf[256];
  const int t = threadIdx.x;
  const int v = (t < G) ? partial[t] : 0;
  buf[t] = v; __syncthreads();
  for (int off = 1; off < 256; off <<= 1) {
    const int x = (t >= off) ? buf[t - off] : 0;
    __syncthreads();
    buf[t] += x;
    __syncthreads();
  }
  if (t < G) partial[t] = buf[t] - v;   // exclusive
}

__global__ __launch_bounds__(256)
void scan_final_k(const int* __restrict__ cnt, const int* __restrict__ partial,
                  int* __restrict__ row_ptr, int* __restrict__ cursor, int M, int E) {
  __shared__ int red[256];
  const int b = blockIdx.x, t = threadIdx.x;
  const int base = b * 1024 + t * 4;
  int v[4]; int s = 0;
#pragma unroll
  for (int i = 0; i < 4; ++i) { const int idx = base + i; v[i] = (idx < M) ? cnt[idx] : 0; s += v[i]; }
  red[t] = s; __syncthreads();
  for (int off = 1; off < 256; off <<= 1) {
    const int x = (t >= off) ? red[t - off] : 0;
    __syncthreads();
    red[t] += x;
    __syncthreads();
  }
  int excl = red[t] - s + partial[b];
#pragma unroll
  for (int i = 0; i < 4; ++i) {
    const int idx = base + i;
    if (idx < M) { row_ptr[idx] = excl; cursor[idx] = excl; excl += v[i]; }
  }
  if (b == 0 && t == 0) row_ptr[M] = E;
}

__global__ __launch_bounds__(256)
void scatter_k(const int* __restrict__ rows, const int* __restrict__ cols,
               const float* __restrict__ vals, int* __restrict__ cursor,
               int* __restrict__ ecol, float* __restrict__ evalv, int E) {
  const int i = blockIdx.x * 256 + threadIdx.x;
  if (i < E) {
    const int r = rows[i];
    const int idx = atomicAdd(&cursor[r], 1);
    ecol[idx] = cols[i];
    evalv[idx] = vals[i];
  }
}

// ---------------- CSR SpMM, D=256: one wave per row, fused bias + relu
__global__ __launch_bounds__(256)
void spmm_csr_d256(const int* __restrict__ rp, const int* __restrict__ ec,
                   const float* __restrict__ ev, const float* __restrict__ dense,
                   const float* __restrict__ bias, float* __restrict__ out, int M) {
  const int wid = (blockIdx.x * 256 + threadIdx.x) >> 6;
  if (wid >= M) return;
  const int lane = threadIdx.x & 63;
  const int d4 = lane << 2;
  const int start = rp[wid], end = rp[wid + 1];
  float4 acc = *(const float4*)(bias + d4);
  for (int j0 = start; j0 < end; j0 += 64) {
    const int jm = min(64, end - j0);
    const int   c = (lane < jm) ? ec[j0 + lane] : 0;
    const float v = (lane < jm) ? ev[j0 + lane] : 0.f;
    for (int kk = 0; kk < jm; ++kk) {
      const int   cc = __shfl(c, kk);
      const float vv = __shfl(v, kk);
      const float4 g = *(const float4*)(dense + (size_t)cc * 256 + d4);
      acc.x += vv * g.x; acc.y += vv * g.y; acc.z += vv * g.z; acc.w += vv * g.w;
    }
  }
  acc.x = fmaxf(acc.x, 0.f); acc.y = fmaxf(acc.y, 0.f);
  acc.z = fmaxf(acc.z, 0.f); acc.w = fmaxf(acc.w, 0.f);
  *(float4*)(out + (size_t)wid * 256 + d4) = acc;
}

// ---------------- CSR SpMM, D=64: one wave per row, fused bias + log_softmax
__global__ __launch_bounds__(256)
void spmm_csr_d64_lsm(const int* __restrict__ rp, const int* __restrict__ ec,
                      const float* __restrict__ ev, const float* __restrict__ dense,
                      const float* __restrict__ bias, float* __restrict__ out, int M) {
  const int wid = (blockIdx.x * 256 + threadIdx.x) >> 6;
  if (wid >= M) return;
  const int lane = threadIdx.x & 63;
  const int start = rp[wid], end = rp[wid + 1];
  float acc = bias[lane];
  for (int j0 = start; j0 < end; j0 += 64) {
    const int jm = min(64, end - j0);
    const int   c = (lane < jm) ? ec[j0 + lane] : 0;
    const float v = (lane < jm) ? ev[j0 + lane] : 0.f;
    for (int kk = 0; kk < jm; ++kk) {
      const int   cc = __shfl(c, kk);
      const float vv = __shfl(v, kk);
      acc += vv * dense[(size_t)cc * 64 + lane];
    }
  }
  float m = acc;
#pragma unroll
  for (int off = 32; off; off >>= 1) m = fmaxf(m, __shfl_xor(m, off));
  const float e = __expf(acc - m);
  float s = e;
#pragma unroll
  for (int off = 32; off; off >>= 1) s += __shfl_xor(s, off);
  out[(size_t)wid * 64 + lane] = acc - m - __logf(s);
}

// ---------------- launch
static inline size_t align256(size_t x) { return (x + 255) & ~(size_t)255; }

extern "C" void kernel_launch(void* const* d_in, const int* in_sizes, int n_in,
                              void* d_out, int out_size, void* d_ws, size_t ws_size,
                              hipStream_t stream) {
  const float* x   = (const float*)d_in[0];
  const int*   a1r = (const int*)d_in[1];
  const int*   a1c = (const int*)d_in[2];
  const float* a1v = (const float*)d_in[3];
  const int*   a2r = (const int*)d_in[4];
  const int*   a2c = (const int*)d_in[5];
  const float* a2v = (const float*)d_in[6];
  const float* W1  = (const float*)d_in[7];
  const float* b1  = (const float*)d_in[8];
  const float* W2  = (const float*)d_in[9];
  const float* b2  = (const float*)d_in[10];
  float* out = (float*)d_out;

  const int M  = in_sizes[0] / NFEAT;   // 100000
  const int E1 = in_sizes[1];           // 3200000
  const int E2 = in_sizes[4];
  const int Emax = (E1 > E2) ? E1 : E2;
  const int G  = (M + 1023) / 1024;     // scan blocks (<=256 required)

  // workspace carve-up
  char* p = (char*)d_ws;
  float* support = (float*)p;                         p += align256((size_t)M * NHID * sizeof(float));
  float* h       = (float*)p;                         p += align256((size_t)M * NHID * sizeof(float));
  int*   cnt     = (int*)p;                           p += align256((size_t)M * sizeof(int));
  int*   row_ptr = (int*)p;                           p += align256((size_t)(M + 1) * sizeof(int));
  int*   cursor  = (int*)p;                           p += align256((size_t)M * sizeof(int));
  int*   partial = (int*)p;                           p += align256(1024 * sizeof(int));
  int*   ecol    = (int*)p;                           p += align256((size_t)Emax * sizeof(int));
  float* evalv   = (float*)p;                         p += align256((size_t)Emax * sizeof(float));

  const int blkM   = (M + 255) / 256;
  const int blkE1  = (E1 + 255) / 256;
  const int blkE2  = (E2 + 255) / 256;
  const int blkRow = (M * 64 + 255) / 256;   // one wave per row

  // 1) support1 = x @ W1
  {
    dim3 grid((M + BM - 1) / BM, NHID / BN);
    gemm_tiled<false><<<grid, 256, 0, stream>>>(x, W1, support, M, NHID, NFEAT);
  }
  // 2) CSR build for adj1
  zero_ints<<<blkM, 256, 0, stream>>>(cnt, M);
  hist_k<<<blkE1, 256, 0, stream>>>(a1r, cnt, E1);
  scan_partial_k<<<G, 256, 0, stream>>>(cnt, partial, M);
  scan_offsets_k<<<1, 256, 0, stream>>>(partial, G);
  scan_final_k<<<G, 256, 0, stream>>>(cnt, partial, row_ptr, cursor, M, E1);
  scatter_k<<<blkE1, 256, 0, stream>>>(a1r, a1c, a1v, cursor, ecol, evalv, E1);
  // 3) h = relu(adj1 @ support1 + b1)
  spmm_csr_d256<<<blkRow, 256, 0, stream>>>(row_ptr, ecol, evalv, support, b1, h, M);
  // 4) support2 = h @ W2
  {
    dim3 grid((M + BM - 1) / BM, NCLASS / BN);
    gemm_tiled<false><<<grid, 256, 0, stream>>>(h, W2, support, M, NCLASS, NHID);
  }
  // 5) CSR build for adj2
  zero_ints<<<blkM, 256, 0, stream>>>(cnt, M);
  hist_k<<<blkE2, 256, 0, stream>>>(a2r, cnt, E2);
  scan_partial_k<<<G, 256, 0, stream>>>(cnt, partial, M);
  scan_offsets_k<<<1, 256, 0, stream>>>(partial, G);
  scan_final_k<<<G, 256, 0, stream>>>(cnt, partial, row_ptr, cursor, M, E2);
  scatter_k<<<blkE2, 256, 0, stream>>>(a2r, a2c, a2v, cursor, ecol, evalv, E2);
  // 6) out = log_softmax(adj2 @ support2 + b2)
  spmm_csr_d64_lsm<<<blkRow, 256, 0, stream>>>(row_ptr, ecol, evalv, support, b2, out, M);
}

// Round 3
// 1185.302 us; speedup vs baseline: 9.9304x; 1.5170x over previous
//
#include <hip/hip_runtime.h>
#include <cstdint>

#define NFEAT 512
#define NHID 256
#define NCLASS 64

typedef __attribute__((ext_vector_type(8))) short bf16x8;
typedef __attribute__((ext_vector_type(4))) float f32x4;

__device__ __forceinline__ unsigned short f2bf(float f) {
  unsigned u = __builtin_bit_cast(unsigned, f);
  u = (u + 0x7FFF + ((u >> 16) & 1)) >> 16;   // RNE
  return (unsigned short)u;
}
__device__ __forceinline__ float bfu(unsigned short u) {
  return __builtin_bit_cast(float, (unsigned)u << 16);
}

// ---------------- weight conversion (once per call, tiny)
__global__ __launch_bounds__(256)
void convert_w1(const float* __restrict__ W, short* __restrict__ WT) { // [512][256] -> [256][512] bf16
  const int idx = blockIdx.x * 256 + threadIdx.x;
  if (idx < 512 * 256) {
    const int k = idx >> 8, n = idx & 255;
    WT[n * 512 + k] = (short)f2bf(W[idx]);
  }
}
__global__ __launch_bounds__(256)
void convert_w2(const float* __restrict__ W, short* __restrict__ WT) { // [256][64] -> [64][256] bf16
  const int idx = blockIdx.x * 256 + threadIdx.x;
  if (idx < 256 * 64) {
    const int k = idx >> 6, n = idx & 63;
    WT[n * 256 + k] = (short)f2bf(W[idx]);
  }
}

// ---------------- GEMM1: C[M][256](bf16) = A[M][512](fp32) @ W1, B given as W1T [256][512] bf16
__global__ __launch_bounds__(256)
void gemm1_mfma(const float* __restrict__ A, const short* __restrict__ BT,
                unsigned short* __restrict__ C, int M) {
  __shared__ short As[128 * 32];            // [row][k] bf16, 8 KB
  const int t    = threadIdx.x;
  const int w    = t >> 6;                  // wave 0..3 -> col block w*64
  const int lane = t & 63;
  const int lr   = lane & 15;
  const int g    = lane >> 4;
  const int bm   = blockIdx.x * 128;

  f32x4 acc[8][4] = {};

  for (int k0 = 0; k0 < NFEAT; k0 += 32) {
    // stage A tile: 512 granules of 16B; granule = p*256 + t
#pragma unroll
    for (int p = 0; p < 2; ++p) {
      const int gran = p * 256 + t;
      const int row  = gran >> 2;
      const int kc   = (gran & 3) << 3;     // 0,8,16,24
      const int grow = bm + row;
      float4 f0 = make_float4(0.f, 0.f, 0.f, 0.f), f1 = f0;
      if (grow < M) {
        const float* src = A + (size_t)grow * NFEAT + k0 + kc;
        f0 = *(const float4*)(src);
        f1 = *(const float4*)(src + 4);
      }
      union { bf16x8 v; unsigned short u[8]; } pk;
      pk.u[0] = f2bf(f0.x); pk.u[1] = f2bf(f0.y); pk.u[2] = f2bf(f0.z); pk.u[3] = f2bf(f0.w);
      pk.u[4] = f2bf(f1.x); pk.u[5] = f2bf(f1.y); pk.u[6] = f2bf(f1.z); pk.u[7] = f2bf(f1.w);
      *(bf16x8*)(&As[gran * 8]) = pk.v;     // short index = row*32 + kc
    }
    __syncthreads();

    bf16x8 bfr[4];
#pragma unroll
    for (int n = 0; n < 4; ++n) {
      const int col = w * 64 + n * 16 + lr;
      bfr[n] = *(const bf16x8*)(BT + (size_t)col * NFEAT + k0 + g * 8);
    }
#pragma unroll
    for (int m = 0; m < 8; ++m) {
      const bf16x8 af = *(const bf16x8*)(&As[(m * 16 + lr) * 32 + g * 8]);
#pragma unroll
      for (int n = 0; n < 4; ++n)
        acc[m][n] = __builtin_amdgcn_mfma_f32_16x16x32_bf16(af, bfr[n], acc[m][n], 0, 0, 0);
    }
    __syncthreads();
  }

#pragma unroll
  for (int m = 0; m < 8; ++m) {
#pragma unroll
    for (int r = 0; r < 4; ++r) {
      const int row = bm + m * 16 + g * 4 + r;
      if (row < M) {
#pragma unroll
        for (int n = 0; n < 4; ++n) {
          const int col = w * 64 + n * 16 + lr;
          C[(size_t)row * NHID + col] = f2bf(acc[m][n][r]);
        }
      }
    }
  }
}

// ---------------- GEMM2: C[M][64](bf16) = A[M][256](bf16) @ W2, B given as W2T [64][256] bf16
__global__ __launch_bounds__(256)
void gemm2_mfma(const unsigned short* __restrict__ A, const short* __restrict__ BT,
                unsigned short* __restrict__ C, int M) {
  __shared__ short As[128 * 32];            // 8 KB
  const int t    = threadIdx.x;
  const int w    = t >> 6;                  // wave 0..3 -> row block w*32
  const int lane = t & 63;
  const int lr   = lane & 15;
  const int g    = lane >> 4;
  const int bm   = blockIdx.x * 128;

  f32x4 acc[2][4] = {};

  for (int k0 = 0; k0 < NHID; k0 += 32) {
#pragma unroll
    for (int p = 0; p < 2; ++p) {
      const int gran = p * 256 + t;
      const int row  = gran >> 2;
      const int kc   = (gran & 3) << 3;
      const int grow = bm + row;
      bf16x8 av = {};
      if (grow < M) av = *(const bf16x8*)(A + (size_t)grow * NHID + k0 + kc);
      *(bf16x8*)(&As[gran * 8]) = av;
    }
    __syncthreads();

    bf16x8 bfr[4];
#pragma unroll
    for (int n = 0; n < 4; ++n) {
      const int col = n * 16 + lr;
      bfr[n] = *(const bf16x8*)(BT + (size_t)col * NHID + k0 + g * 8);
    }
#pragma unroll
    for (int m = 0; m < 2; ++m) {
      const bf16x8 af = *(const bf16x8*)(&As[(w * 32 + m * 16 + lr) * 32 + g * 8]);
#pragma unroll
      for (int n = 0; n < 4; ++n)
        acc[m][n] = __builtin_amdgcn_mfma_f32_16x16x32_bf16(af, bfr[n], acc[m][n], 0, 0, 0);
    }
    __syncthreads();
  }

#pragma unroll
  for (int m = 0; m < 2; ++m) {
#pragma unroll
    for (int r = 0; r < 4; ++r) {
      const int row = bm + w * 32 + m * 16 + g * 4 + r;
      if (row < M) {
#pragma unroll
        for (int n = 0; n < 4; ++n) {
          const int col = n * 16 + lr;
          C[(size_t)row * NCLASS + col] = f2bf(acc[m][n][r]);
        }
      }
    }
  }
}

// ---------------- CSR build: zero, histogram, 3-phase scan, scatter
__global__ __launch_bounds__(256)
void zero_ints(int* __restrict__ p, int n) {
  const int i = blockIdx.x * 256 + threadIdx.x;
  if (i < n) p[i] = 0;
}

__global__ __launch_bounds__(256)
void hist_k(const int* __restrict__ rows, int* __restrict__ cnt, int E) {
  const int i = blockIdx.x * 256 + threadIdx.x;
  if (i < E) atomicAdd(&cnt[rows[i]], 1);
}

__global__ __launch_bounds__(256)
void scan_partial_k(const int* __restrict__ cnt, int* __restrict__ partial, int M) {
  __shared__ int red[256];
  const int b = blockIdx.x, t = threadIdx.x;
  const int base = b * 1024 + t * 4;
  int s = 0;
#pragma unroll
  for (int i = 0; i < 4; ++i) { const int idx = base + i; if (idx < M) s += cnt[idx]; }
  red[t] = s; __syncthreads();
  for (int off = 128; off; off >>= 1) { if (t < off) red[t] += red[t + off]; __syncthreads(); }
  if (t == 0) partial[b] = red[0];
}

__global__ __launch_bounds__(256)
void scan_offsets_k(int* __restrict__ partial, int G) {
  __shared__ int buf[256];
  const int t = threadIdx.x;
  const int v = (t < G) ? partial[t] : 0;
  buf[t] = v; __syncthreads();
  for (int off = 1; off < 256; off <<= 1) {
    const int x = (t >= off) ? buf[t - off] : 0;
    __syncthreads();
    buf[t] += x;
    __syncthreads();
  }
  if (t < G) partial[t] = buf[t] - v;
}

__global__ __launch_bounds__(256)
void scan_final_k(const int* __restrict__ cnt, const int* __restrict__ partial,
                  int* __restrict__ row_ptr, int* __restrict__ cursor, int M, int E) {
  __shared__ int red[256];
  const int b = blockIdx.x, t = threadIdx.x;
  const int base = b * 1024 + t * 4;
  int v[4]; int s = 0;
#pragma unroll
  for (int i = 0; i < 4; ++i) { const int idx = base + i; v[i] = (idx < M) ? cnt[idx] : 0; s += v[i]; }
  red[t] = s; __syncthreads();
  for (int off = 1; off < 256; off <<= 1) {
    const int x = (t >= off) ? red[t - off] : 0;
    __syncthreads();
    red[t] += x;
    __syncthreads();
  }
  int excl = red[t] - s + partial[b];
#pragma unroll
  for (int i = 0; i < 4; ++i) {
    const int idx = base + i;
    if (idx < M) { row_ptr[idx] = excl; cursor[idx] = excl; excl += v[i]; }
  }
  if (b == 0 && t == 0) row_ptr[M] = E;
}

__global__ __launch_bounds__(256)
void scatter_k(const int* __restrict__ rows, const int* __restrict__ cols,
               const float* __restrict__ vals, int* __restrict__ cursor,
               int* __restrict__ ecol, float* __restrict__ evalv, int E) {
  const int i = blockIdx.x * 256 + threadIdx.x;
  if (i < E) {
    const int r = rows[i];
    const int idx = atomicAdd(&cursor[r], 1);
    ecol[idx] = cols[i];
    evalv[idx] = vals[i];
  }
}

// ---------------- CSR SpMM D=256 bf16: one wave per row, fused bias + relu, bf16 out
__global__ __launch_bounds__(256)
void spmm_csr_d256_bf(const int* __restrict__ rp, const int* __restrict__ ec,
                      const float* __restrict__ ev, const unsigned short* __restrict__ dense,
                      const float* __restrict__ bias, unsigned short* __restrict__ out, int M) {
  const int wid = (blockIdx.x * 256 + threadIdx.x) >> 6;
  if (wid >= M) return;
  const int lane = threadIdx.x & 63;
  const int d4 = lane << 2;
  const int start = rp[wid], end = rp[wid + 1];
  float4 acc = *(const float4*)(bias + d4);
  for (int j0 = start; j0 < end; j0 += 64) {
    const int jm = min(64, end - j0);
    const int jr = (jm + 7) & ~7;
    const int   c = (lane < jm) ? ec[j0 + lane] : 0;
    const float v = (lane < jm) ? ev[j0 + lane] : 0.f;
    for (int kk = 0; kk < jr; kk += 8) {
#pragma unroll
      for (int u = 0; u < 8; ++u) {
        const int   cc = __shfl(c, kk + u);
        const float vv = __shfl(v, kk + u);
        const ushort4 gg = *(const ushort4*)(dense + (size_t)cc * NHID + d4);
        acc.x += vv * bfu(gg.x); acc.y += vv * bfu(gg.y);
        acc.z += vv * bfu(gg.z); acc.w += vv * bfu(gg.w);
      }
    }
  }
  ushort4 o;
  o.x = f2bf(fmaxf(acc.x, 0.f)); o.y = f2bf(fmaxf(acc.y, 0.f));
  o.z = f2bf(fmaxf(acc.z, 0.f)); o.w = f2bf(fmaxf(acc.w, 0.f));
  *(ushort4*)(out + (size_t)wid * NHID + d4) = o;
}

// ---------------- CSR SpMM D=64 bf16: one wave per row, fused bias + log_softmax, fp32 out
__global__ __launch_bounds__(256)
void spmm_csr_d64_lsm_bf(const int* __restrict__ rp, const int* __restrict__ ec,
                         const float* __restrict__ ev, const unsigned short* __restrict__ dense,
                         const float* __restrict__ bias, float* __restrict__ out, int M) {
  const int wid = (blockIdx.x * 256 + threadIdx.x) >> 6;
  if (wid >= M) return;
  const int lane = threadIdx.x & 63;
  const int start = rp[wid], end = rp[wid + 1];
  float acc = bias[lane];
  for (int j0 = start; j0 < end; j0 += 64) {
    const int jm = min(64, end - j0);
    const int jr = (jm + 7) & ~7;
    const int   c = (lane < jm) ? ec[j0 + lane] : 0;
    const float v = (lane < jm) ? ev[j0 + lane] : 0.f;
    for (int kk = 0; kk < jr; kk += 8) {
#pragma unroll
      for (int u = 0; u < 8; ++u) {
        const int   cc = __shfl(c, kk + u);
        const float vv = __shfl(v, kk + u);
        acc += vv * bfu(dense[(size_t)cc * NCLASS + lane]);
      }
    }
  }
  float m = acc;
#pragma unroll
  for (int off = 32; off; off >>= 1) m = fmaxf(m, __shfl_xor(m, off));
  const float e = __expf(acc - m);
  float s = e;
#pragma unroll
  for (int off = 32; off; off >>= 1) s += __shfl_xor(s, off);
  out[(size_t)wid * NCLASS + lane] = acc - m - __logf(s);
}

// ---------------- launch
static inline size_t align256(size_t x) { return (x + 255) & ~(size_t)255; }

extern "C" void kernel_launch(void* const* d_in, const int* in_sizes, int n_in,
                              void* d_out, int out_size, void* d_ws, size_t ws_size,
                              hipStream_t stream) {
  const float* x   = (const float*)d_in[0];
  const int*   a1r = (const int*)d_in[1];
  const int*   a1c = (const int*)d_in[2];
  const float* a1v = (const float*)d_in[3];
  const int*   a2r = (const int*)d_in[4];
  const int*   a2c = (const int*)d_in[5];
  const float* a2v = (const float*)d_in[6];
  const float* W1  = (const float*)d_in[7];
  const float* b1  = (const float*)d_in[8];
  const float* W2  = (const float*)d_in[9];
  const float* b2  = (const float*)d_in[10];
  float* out = (float*)d_out;

  const int M  = in_sizes[0] / NFEAT;   // 100000
  const int E1 = in_sizes[1];
  const int E2 = in_sizes[4];
  const int Emax = (E1 > E2) ? E1 : E2;
  const int G  = (M + 1023) / 1024;

  char* p = (char*)d_ws;
  unsigned short* s1   = (unsigned short*)p;  p += align256((size_t)M * NHID * sizeof(short));
  unsigned short* h    = (unsigned short*)p;  p += align256((size_t)M * NHID * sizeof(short));
  unsigned short* s2   = (unsigned short*)p;  p += align256((size_t)M * NCLASS * sizeof(short));
  short* W1T           = (short*)p;           p += align256((size_t)NFEAT * NHID * sizeof(short));
  short* W2T           = (short*)p;           p += align256((size_t)NHID * NCLASS * sizeof(short));
  int*   cnt           = (int*)p;             p += align256((size_t)M * sizeof(int));
  int*   row_ptr       = (int*)p;             p += align256((size_t)(M + 1) * sizeof(int));
  int*   cursor        = (int*)p;             p += align256((size_t)M * sizeof(int));
  int*   partial       = (int*)p;             p += align256(1024 * sizeof(int));
  int*   ecol          = (int*)p;             p += align256((size_t)Emax * sizeof(int));
  float* evalv         = (float*)p;           p += align256((size_t)Emax * sizeof(float));

  const int blkM   = (M + 255) / 256;
  const int blkE1  = (E1 + 255) / 256;
  const int blkE2  = (E2 + 255) / 256;
  const int blkRow = (M * 64 + 255) / 256;
  const int blkG   = (M + 127) / 128;

  // 0) weight conversions
  convert_w1<<<(512 * 256 + 255) / 256, 256, 0, stream>>>(W1, W1T);
  convert_w2<<<(256 * 64 + 255) / 256, 256, 0, stream>>>(W2, W2T);

  // 1) support1 = bf16(x @ W1)
  gemm1_mfma<<<blkG, 256, 0, stream>>>(x, W1T, s1, M);

  // 2) CSR build for adj1
  zero_ints<<<blkM, 256, 0, stream>>>(cnt, M);
  hist_k<<<blkE1, 256, 0, stream>>>(a1r, cnt, E1);
  scan_partial_k<<<G, 256, 0, stream>>>(cnt, partial, M);
  scan_offsets_k<<<1, 256, 0, stream>>>(partial, G);
  scan_final_k<<<G, 256, 0, stream>>>(cnt, partial, row_ptr, cursor, M, E1);
  scatter_k<<<blkE1, 256, 0, stream>>>(a1r, a1c, a1v, cursor, ecol, evalv, E1);

  // 3) h = bf16(relu(adj1 @ support1 + b1))
  spmm_csr_d256_bf<<<blkRow, 256, 0, stream>>>(row_ptr, ecol, evalv, s1, b1, h, M);

  // 4) support2 = bf16(h @ W2)
  gemm2_mfma<<<blkG, 256, 0, stream>>>(h, W2T, s2, M);

  // 5) CSR build for adj2
  zero_ints<<<blkM, 256, 0, stream>>>(cnt, M);
  hist_k<<<blkE2, 256, 0, stream>>>(a2r, cnt, E2);
  scan_partial_k<<<G, 256, 0, stream>>>(cnt, partial, M);
  scan_offsets_k<<<1, 256, 0, stream>>>(partial, G);
  scan_final_k<<<G, 256, 0, stream>>>(cnt, partial, row_ptr, cursor, M, E2);
  scatter_k<<<blkE2, 256, 0, stream>>>(a2r, a2c, a2v, cursor, ecol, evalv, E2);

  // 6) out = log_softmax(adj2 @ support2 + b2)
  spmm_csr_d64_lsm_bf<<<blkRow, 256, 0, stream>>>(row_ptr, ecol, evalv, s2, b2, out, M);
}

// Round 4
// 1061.775 us; speedup vs baseline: 11.0857x; 1.1163x over previous
//
#include <hip/hip_runtime.h>
#include <cstdint>

#define NFEAT 512
#define NHID 256
#define NCLASS 64

typedef __attribute__((ext_vector_type(8))) short bf16x8;
typedef __attribute__((ext_vector_type(4))) float f32x4;

__device__ __forceinline__ unsigned short f2bf(float f) {
  unsigned u = __builtin_bit_cast(unsigned, f);
  u = (u + 0x7FFF + ((u >> 16) & 1)) >> 16;   // RNE
  return (unsigned short)u;
}
__device__ __forceinline__ float bfu(unsigned short u) {
  return __builtin_bit_cast(float, (unsigned)u << 16);
}

// ---------------- weight conversion (fused, once per call, tiny)
__global__ __launch_bounds__(256)
void convert_w12(const float* __restrict__ W1, short* __restrict__ W1T,
                 const float* __restrict__ W2, short* __restrict__ W2T) {
  const int idx = blockIdx.x * 256 + threadIdx.x;
  if (idx < 512 * 256) {
    const int k = idx >> 8, n = idx & 255;
    W1T[n * 512 + k] = (short)f2bf(W1[idx]);
  }
  if (idx < 256 * 64) {
    const int k = idx >> 6, n = idx & 63;
    W2T[n * 256 + k] = (short)f2bf(W2[idx]);
  }
}

// ---------------- GEMM1: C[M][256](bf16) = A[M][512](fp32) @ W1, B = W1T [256][512] bf16
__global__ __launch_bounds__(256)
void gemm1_mfma(const float* __restrict__ A, const short* __restrict__ BT,
                unsigned short* __restrict__ C, int M) {
  __shared__ short As[128 * 32];            // [row][k] bf16, 8 KB
  const int t    = threadIdx.x;
  const int w    = t >> 6;
  const int lane = t & 63;
  const int lr   = lane & 15;
  const int g    = lane >> 4;
  const int bm   = blockIdx.x * 128;

  f32x4 acc[8][4] = {};

  for (int k0 = 0; k0 < NFEAT; k0 += 32) {
#pragma unroll
    for (int p = 0; p < 2; ++p) {
      const int gran = p * 256 + t;
      const int row  = gran >> 2;
      const int kc   = (gran & 3) << 3;
      const int grow = bm + row;
      float4 f0 = make_float4(0.f, 0.f, 0.f, 0.f), f1 = f0;
      if (grow < M) {
        const float* src = A + (size_t)grow * NFEAT + k0 + kc;
        f0 = *(const float4*)(src);
        f1 = *(const float4*)(src + 4);
      }
      union { bf16x8 v; unsigned short u[8]; } pk;
      pk.u[0] = f2bf(f0.x); pk.u[1] = f2bf(f0.y); pk.u[2] = f2bf(f0.z); pk.u[3] = f2bf(f0.w);
      pk.u[4] = f2bf(f1.x); pk.u[5] = f2bf(f1.y); pk.u[6] = f2bf(f1.z); pk.u[7] = f2bf(f1.w);
      *(bf16x8*)(&As[gran * 8]) = pk.v;
    }
    __syncthreads();

    bf16x8 bfr[4];
#pragma unroll
    for (int n = 0; n < 4; ++n) {
      const int col = w * 64 + n * 16 + lr;
      bfr[n] = *(const bf16x8*)(BT + (size_t)col * NFEAT + k0 + g * 8);
    }
#pragma unroll
    for (int m = 0; m < 8; ++m) {
      const bf16x8 af = *(const bf16x8*)(&As[(m * 16 + lr) * 32 + g * 8]);
#pragma unroll
      for (int n = 0; n < 4; ++n)
        acc[m][n] = __builtin_amdgcn_mfma_f32_16x16x32_bf16(af, bfr[n], acc[m][n], 0, 0, 0);
    }
    __syncthreads();
  }

#pragma unroll
  for (int m = 0; m < 8; ++m) {
#pragma unroll
    for (int r = 0; r < 4; ++r) {
      const int row = bm + m * 16 + g * 4 + r;
      if (row < M) {
#pragma unroll
        for (int n = 0; n < 4; ++n) {
          const int col = w * 64 + n * 16 + lr;
          C[(size_t)row * NHID + col] = f2bf(acc[m][n][r]);
        }
      }
    }
  }
}

// ---------------- GEMM2: C[M][64](bf16) = A[M][256](bf16) @ W2, B = W2T [64][256] bf16
__global__ __launch_bounds__(256)
void gemm2_mfma(const unsigned short* __restrict__ A, const short* __restrict__ BT,
                unsigned short* __restrict__ C, int M) {
  __shared__ short As[128 * 32];
  const int t    = threadIdx.x;
  const int w    = t >> 6;
  const int lane = t & 63;
  const int lr   = lane & 15;
  const int g    = lane >> 4;
  const int bm   = blockIdx.x * 128;

  f32x4 acc[2][4] = {};

  for (int k0 = 0; k0 < NHID; k0 += 32) {
#pragma unroll
    for (int p = 0; p < 2; ++p) {
      const int gran = p * 256 + t;
      const int row  = gran >> 2;
      const int kc   = (gran & 3) << 3;
      const int grow = bm + row;
      bf16x8 av = {};
      if (grow < M) av = *(const bf16x8*)(A + (size_t)grow * NHID + k0 + kc);
      *(bf16x8*)(&As[gran * 8]) = av;
    }
    __syncthreads();

    bf16x8 bfr[4];
#pragma unroll
    for (int n = 0; n < 4; ++n) {
      const int col = n * 16 + lr;
      bfr[n] = *(const bf16x8*)(BT + (size_t)col * NHID + k0 + g * 8);
    }
#pragma unroll
    for (int m = 0; m < 2; ++m) {
      const bf16x8 af = *(const bf16x8*)(&As[(w * 32 + m * 16 + lr) * 32 + g * 8]);
#pragma unroll
      for (int n = 0; n < 4; ++n)
        acc[m][n] = __builtin_amdgcn_mfma_f32_16x16x32_bf16(af, bfr[n], acc[m][n], 0, 0, 0);
    }
    __syncthreads();
  }

#pragma unroll
  for (int m = 0; m < 2; ++m) {
#pragma unroll
    for (int r = 0; r < 4; ++r) {
      const int row = bm + w * 32 + m * 16 + g * 4 + r;
      if (row < M) {
#pragma unroll
        for (int n = 0; n < 4; ++n) {
          const int col = n * 16 + lr;
          C[(size_t)row * NCLASS + col] = f2bf(acc[m][n][r]);
        }
      }
    }
  }
}

// ---------------- fused CSR build for BOTH adjacencies
__global__ __launch_bounds__(256)
void zero2_k(int* __restrict__ p, int n) {
  const int i = blockIdx.x * 256 + threadIdx.x;
  if (i < n) p[i] = 0;
}

__global__ __launch_bounds__(256)
void hist2_k(const int* __restrict__ r1, const int* __restrict__ r2,
             int* __restrict__ cnt, int M, int E1, int E2) {
  const int i = blockIdx.x * 256 + threadIdx.x;
  if (i < E1) atomicAdd(&cnt[r1[i]], 1);
  else if (i < E1 + E2) atomicAdd(&cnt[M + r2[i - E1]], 1);
}

// grid (G, 2)
__global__ __launch_bounds__(256)
void scan_partial_k(const int* __restrict__ cnt, int* __restrict__ partial, int M) {
  __shared__ int red[256];
  const int b = blockIdx.x, t = threadIdx.x, seg = blockIdx.y;
  const int* cs = cnt + (size_t)seg * M;
  const int base = b * 1024 + t * 4;
  int s = 0;
#pragma unroll
  for (int i = 0; i < 4; ++i) { const int idx = base + i; if (idx < M) s += cs[idx]; }
  red[t] = s; __syncthreads();
  for (int off = 128; off; off >>= 1) { if (t < off) red[t] += red[t + off]; __syncthreads(); }
  if (t == 0) partial[seg * 256 + b] = red[0];
}

// grid (2): one block per segment
__global__ __launch_bounds__(256)
void scan_offsets_k(int* __restrict__ partial, int G) {
  __shared__ int buf[256];
  const int t = threadIdx.x;
  int* ps = partial + blockIdx.x * 256;
  const int v = (t < G) ? ps[t] : 0;
  buf[t] = v; __syncthreads();
  for (int off = 1; off < 256; off <<= 1) {
    const int x = (t >= off) ? buf[t - off] : 0;
    __syncthreads();
    buf[t] += x;
    __syncthreads();
  }
  if (t < G) ps[t] = buf[t] - v;
}

// grid (G, 2)
__global__ __launch_bounds__(256)
void scan_final_k(const int* __restrict__ cnt, const int* __restrict__ partial,
                  int* __restrict__ row_ptr, int* __restrict__ cursor,
                  int M, int E1, int E2) {
  __shared__ int red[256];
  const int b = blockIdx.x, t = threadIdx.x, seg = blockIdx.y;
  const int* cs   = cnt + (size_t)seg * M;
  int* rps        = row_ptr + (size_t)seg * (M + 1);
  int* curs       = cursor + (size_t)seg * M;
  const int E     = seg == 0 ? E1 : E2;
  const int base  = b * 1024 + t * 4;
  int v[4]; int s = 0;
#pragma unroll
  for (int i = 0; i < 4; ++i) { const int idx = base + i; v[i] = (idx < M) ? cs[idx] : 0; s += v[i]; }
  red[t] = s; __syncthreads();
  for (int off = 1; off < 256; off <<= 1) {
    const int x = (t >= off) ? red[t - off] : 0;
    __syncthreads();
    red[t] += x;
    __syncthreads();
  }
  int excl = red[t] - s + partial[seg * 256 + b];
#pragma unroll
  for (int i = 0; i < 4; ++i) {
    const int idx = base + i;
    if (idx < M) { rps[idx] = excl; curs[idx] = excl; excl += v[i]; }
  }
  if (b == 0 && t == 0) rps[M] = E;
}

// fused scatter: packed 8B payload (val<<32 | col), one random store per edge
__global__ __launch_bounds__(256)
void scatter2_k(const int* __restrict__ r1, const int* __restrict__ c1, const float* __restrict__ v1,
                const int* __restrict__ r2, const int* __restrict__ c2, const float* __restrict__ v2,
                int* __restrict__ cursor, unsigned long long* __restrict__ ecv1,
                unsigned long long* __restrict__ ecv2, int M, int E1, int E2) {
  const int i = blockIdx.x * 256 + threadIdx.x;
  if (i < E1) {
    const int r = r1[i];
    const unsigned long long pk =
        ((unsigned long long)__builtin_bit_cast(unsigned, v1[i]) << 32) | (unsigned)c1[i];
    const int idx = atomicAdd(&cursor[r], 1);
    ecv1[idx] = pk;
  } else if (i < E1 + E2) {
    const int j = i - E1;
    const int r = r2[j];
    const unsigned long long pk =
        ((unsigned long long)__builtin_bit_cast(unsigned, v2[j]) << 32) | (unsigned)c2[j];
    const int idx = atomicAdd(&cursor[M + r], 1);
    ecv2[idx] = pk;
  }
}

// ---------------- CSR SpMM D=256 bf16: one wave/row, packed payload, fused bias+relu
__global__ __launch_bounds__(256)
void spmm_csr_d256_bf(const int* __restrict__ rp, const unsigned long long* __restrict__ ecv,
                      const unsigned short* __restrict__ dense,
                      const float* __restrict__ bias, unsigned short* __restrict__ out, int M) {
  const int wid = (blockIdx.x * 256 + threadIdx.x) >> 6;
  if (wid >= M) return;
  const int lane = threadIdx.x & 63;
  const int d4 = lane << 2;
  const int start = rp[wid], end = rp[wid + 1];
  float4 acc[2];
  acc[0] = *(const float4*)(bias + d4);
  acc[1] = make_float4(0.f, 0.f, 0.f, 0.f);
  for (int j0 = start; j0 < end; j0 += 64) {
    const int jm = min(64, end - j0);
    const int jr = (jm + 7) & ~7;
    const unsigned long long pk = (lane < jm) ? ecv[j0 + lane] : 0ULL;
    for (int kk = 0; kk < jr; kk += 8) {
#pragma unroll
      for (int u = 0; u < 8; ++u) {
        const unsigned long long pp = __shfl(pk, kk + u);
        const int   cc = (int)(unsigned)pp;
        const float vv = __builtin_bit_cast(float, (unsigned)(pp >> 32));
        const ushort4 gg = *(const ushort4*)(dense + (size_t)cc * NHID + d4);
        acc[u & 1].x += vv * bfu(gg.x); acc[u & 1].y += vv * bfu(gg.y);
        acc[u & 1].z += vv * bfu(gg.z); acc[u & 1].w += vv * bfu(gg.w);
      }
    }
  }
  ushort4 o;
  o.x = f2bf(fmaxf(acc[0].x + acc[1].x, 0.f)); o.y = f2bf(fmaxf(acc[0].y + acc[1].y, 0.f));
  o.z = f2bf(fmaxf(acc[0].z + acc[1].z, 0.f)); o.w = f2bf(fmaxf(acc[0].w + acc[1].w, 0.f));
  *(ushort4*)(out + (size_t)wid * NHID + d4) = o;
}

// ---------------- CSR SpMM D=64 bf16: one wave/row, packed payload, fused bias+log_softmax
__global__ __launch_bounds__(256)
void spmm_csr_d64_lsm_bf(const int* __restrict__ rp, const unsigned long long* __restrict__ ecv,
                         const unsigned short* __restrict__ dense,
                         const float* __restrict__ bias, float* __restrict__ out, int M) {
  const int wid = (blockIdx.x * 256 + threadIdx.x) >> 6;
  if (wid >= M) return;
  const int lane = threadIdx.x & 63;
  const int start = rp[wid], end = rp[wid + 1];
  float acc0 = bias[lane], acc1 = 0.f;
  for (int j0 = start; j0 < end; j0 += 64) {
    const int jm = min(64, end - j0);
    const int jr = (jm + 7) & ~7;
    const unsigned long long pk = (lane < jm) ? ecv[j0 + lane] : 0ULL;
    for (int kk = 0; kk < jr; kk += 8) {
#pragma unroll
      for (int u = 0; u < 8; ++u) {
        const unsigned long long pp = __shfl(pk, kk + u);
        const int   cc = (int)(unsigned)pp;
        const float vv = __builtin_bit_cast(float, (unsigned)(pp >> 32));
        const float gv = bfu(dense[(size_t)cc * NCLASS + lane]);
        if (u & 1) acc1 += vv * gv; else acc0 += vv * gv;
      }
    }
  }
  const float acc = acc0 + acc1;
  float m = acc;
#pragma unroll
  for (int off = 32; off; off >>= 1) m = fmaxf(m, __shfl_xor(m, off));
  const float e = __expf(acc - m);
  float s = e;
#pragma unroll
  for (int off = 32; off; off >>= 1) s += __shfl_xor(s, off);
  out[(size_t)wid * NCLASS + lane] = acc - m - __logf(s);
}

// ---------------- launch
static inline size_t align256(size_t x) { return (x + 255) & ~(size_t)255; }

extern "C" void kernel_launch(void* const* d_in, const int* in_sizes, int n_in,
                              void* d_out, int out_size, void* d_ws, size_t ws_size,
                              hipStream_t stream) {
  const float* x   = (const float*)d_in[0];
  const int*   a1r = (const int*)d_in[1];
  const int*   a1c = (const int*)d_in[2];
  const float* a1v = (const float*)d_in[3];
  const int*   a2r = (const int*)d_in[4];
  const int*   a2c = (const int*)d_in[5];
  const float* a2v = (const float*)d_in[6];
  const float* W1  = (const float*)d_in[7];
  const float* b1  = (const float*)d_in[8];
  const float* W2  = (const float*)d_in[9];
  const float* b2  = (const float*)d_in[10];
  float* out = (float*)d_out;

  const int M  = in_sizes[0] / NFEAT;
  const int E1 = in_sizes[1];
  const int E2 = in_sizes[4];
  const int G  = (M + 1023) / 1024;

  char* p = (char*)d_ws;
  unsigned short* s1  = (unsigned short*)p;        p += align256((size_t)M * NHID * sizeof(short));
  unsigned short* h   = (unsigned short*)p;        p += align256((size_t)M * NHID * sizeof(short));
  unsigned short* s2  = (unsigned short*)p;        p += align256((size_t)M * NCLASS * sizeof(short));
  short* W1T          = (short*)p;                 p += align256((size_t)NFEAT * NHID * sizeof(short));
  short* W2T          = (short*)p;                 p += align256((size_t)NHID * NCLASS * sizeof(short));
  int*   cnt          = (int*)p;                   p += align256((size_t)2 * M * sizeof(int));
  int*   row_ptr      = (int*)p;                   p += align256((size_t)2 * (M + 1) * sizeof(int));
  int*   cursor       = (int*)p;                   p += align256((size_t)2 * M * sizeof(int));
  int*   partial      = (int*)p;                   p += align256(512 * sizeof(int));
  unsigned long long* ecv1 = (unsigned long long*)p; p += align256((size_t)E1 * 8);
  unsigned long long* ecv2 = (unsigned long long*)p; p += align256((size_t)E2 * 8);

  const int blkRow = (M * 64 + 255) / 256;
  const int blkG   = (M + 127) / 128;
  const int blkEE  = (E1 + E2 + 255) / 256;

  // 0) weight conversions
  convert_w12<<<(512 * 256 + 255) / 256, 256, 0, stream>>>(W1, W1T, W2, W2T);
  // 1) CSR build for both adjacencies (fused dispatches)
  zero2_k<<<(2 * M + 255) / 256, 256, 0, stream>>>(cnt, 2 * M);
  hist2_k<<<blkEE, 256, 0, stream>>>(a1r, a2r, cnt, M, E1, E2);
  {
    dim3 gP(G, 2);
    scan_partial_k<<<gP, 256, 0, stream>>>(cnt, partial, M);
    scan_offsets_k<<<2, 256, 0, stream>>>(partial, G);
    scan_final_k<<<gP, 256, 0, stream>>>(cnt, partial, row_ptr, cursor, M, E1, E2);
  }
  scatter2_k<<<blkEE, 256, 0, stream>>>(a1r, a1c, a1v, a2r, a2c, a2v,
                                        cursor, ecv1, ecv2, M, E1, E2);
  // 2) support1 = bf16(x @ W1)
  gemm1_mfma<<<blkG, 256, 0, stream>>>(x, W1T, s1, M);
  // 3) h = bf16(relu(adj1 @ support1 + b1))
  spmm_csr_d256_bf<<<blkRow, 256, 0, stream>>>(row_ptr, ecv1, s1, b1, h, M);
  // 4) support2 = bf16(h @ W2)
  gemm2_mfma<<<blkG, 256, 0, stream>>>(h, W2T, s2, M);
  // 5) out = log_softmax(adj2 @ support2 + b2)
  spmm_csr_d64_lsm_bf<<<blkRow, 256, 0, stream>>>(row_ptr + (M + 1), ecv2, s2, b2, out, M);
}